// Round 8
// baseline (304.196 us; speedup 1.0000x reference)
//
#include <hip/hip_runtime.h>
#include <hip/hip_bf16.h>
#include <math.h>

#define NBOX 19
#define NEDGE 171
#define TT 5
#define BATCH 2048
#define GB 2                  // batches per fused block
#define MR (GB * NBOX)        // 38 real rows per block
#define MP 48                 // padded rows (3 M-tiles of 16)

typedef __attribute__((ext_vector_type(8))) short short8v;
typedef __attribute__((ext_vector_type(4))) float f32x4;

// cheap bf16 convert: round-half-up (2 VALU ops vs ~5 for RNE)
static __device__ __forceinline__ ushort f2bf(float f) {
    unsigned int u = __builtin_bit_cast(unsigned int, f);
    return (ushort)((u + 0x8000u) >> 16);
}

// pack two floats as bf16x2 (lo = a, hi = b)
static __device__ __forceinline__ unsigned pack2bf(float a, float b) {
    unsigned ua = (__builtin_bit_cast(unsigned, a) + 0x8000u) >> 16;
    unsigned ub = (__builtin_bit_cast(unsigned, b) + 0x8000u) & 0xFFFF0000u;
    return ua | ub;
}

static __device__ __forceinline__ float sigm(float x) {
    return __builtin_amdgcn_rcpf(1.0f + __expf(-x));
}

__device__ __forceinline__ int edge_index(int r, int c) {
    return r * (NBOX - 1) - (r * (r - 1)) / 2 + (c - r - 1);
}

// ---------------------------------------------------------------------------
// K1: per-batch normalized adjacency, bf16, padded to 32x32
// ---------------------------------------------------------------------------
__global__ __launch_bounds__(192) void adjbf_kernel(
    const float* __restrict__ loc,
    const int*   __restrict__ mask,
    const float* __restrict__ past,
    ushort* __restrict__ adjbf)
{
    int b = blockIdx.x;
    int tid = threadIdx.x;
    __shared__ float cx[NBOX], cy[NBOX], x0[NBOX], y0[NBOX], ndx[NBOX], ndy[NBOX];
    __shared__ int   mv[NBOX];
    __shared__ float w[NEDGE];
    __shared__ float dinv[NBOX];
    __shared__ float wmin_s, wmax_s;

    if (tid < NBOX) {
        const float* l = loc + ((size_t)b * NBOX + tid) * 5;
        cx[tid] = 0.5f * (l[1] + l[3]);
        cy[tid] = 0.5f * (l[2] + l[4]);
        const float* p0 = past + (((size_t)b * TT + 0) * NBOX + tid) * 6;
        const float* p4 = past + (((size_t)b * TT + (TT - 1)) * NBOX + tid) * 6;
        float cpx0 = (p0[3] - p0[1]) * 1280.0f, cpy0 = (p0[4] - p0[2]) * 720.0f;
        float cpx4 = (p4[3] - p4[1]) * 1280.0f, cpy4 = (p4[4] - p4[2]) * 720.0f;
        float dx = cpx4 - cpx0, dy = cpy4 - cpy0;
        float len = sqrtf(dx * dx + dy * dy);
        if (len == 0.0f) len = 1.0f;
        ndx[tid] = dx / len;
        ndy[tid] = dy / len;
        x0[tid] = cpx0;
        y0[tid] = cpy0;
        mv[tid] = mask[(size_t)b * NBOX + tid];
    }
    __syncthreads();

    float wv = 0.0f;
    if (tid < NEDGE) {
        int rem = tid, rr = 0;
        while (rem >= NBOX - 1 - rr) { rem -= NBOX - 1 - rr; rr++; }
        int r = rr, c = rr + 1 + rem;
        float ddx = cx[r] - cx[c], ddy = cy[r] - cy[c];
        float d = ddx * ddx + ddy * ddy;
        float ax = x0[r] + ndx[r] - x0[c] - ndx[c];
        float ay = y0[r] + ndy[r] - y0[c] - ndy[c];
        float d1 = sqrtf(ax * ax + ay * ay);
        float bx = x0[r] - x0[c], by = y0[r] - y0[c];
        float d2 = sqrtf(bx * bx + by * by);
        float md = d1 - d2;
        wv = expf(-(0.7f * d + 0.3f * md));
        if (!(mv[r] && mv[c])) wv = 0.0f;
        w[tid] = wv;
    }
    __syncthreads();

    if (tid == 0) {
        float mn = w[0], mx = w[0];
        for (int i = 1; i < NEDGE; i++) { mn = fminf(mn, w[i]); mx = fmaxf(mx, w[i]); }
        wmin_s = mn; wmax_s = mx;
    }
    __syncthreads();

    float inv_range = 1.0f / (wmax_s - wmin_s);
    if (tid < NEDGE) w[tid] = (wv - wmin_s) * inv_range;
    __syncthreads();

    if (tid < NBOX) {
        float s = 1.0f;
        for (int rr = 0; rr < tid; rr++) s += w[edge_index(rr, tid)];
        dinv[tid] = 1.0f / sqrtf(s);
    }
    __syncthreads();

    ushort* A = adjbf + (size_t)b * 1024;
    for (int idx = tid; idx < 1024; idx += 192) {
        int r = idx & 31, cc = idx >> 5;
        float v = 0.0f;
        if (r < NBOX && cc < NBOX) {
            if (r == cc) v = dinv[r] * dinv[r];
            else if (r < cc) v = w[edge_index(r, cc)] * dinv[r] * dinv[cc];
        }
        A[idx] = f2bf(v);
    }
}

// ---------------------------------------------------------------------------
// K2: transpose + cvt weights: dst[n*K+k] = bf16(src[k*N+n])
// ---------------------------------------------------------------------------
__global__ void packT_kernel(const float* __restrict__ src, ushort* __restrict__ dst,
                             int K, int N)
{
    int total = K * N;
    for (int idx = blockIdx.x * blockDim.x + threadIdx.x; idx < total;
         idx += gridDim.x * blockDim.x) {
        int n = idx / K, k = idx % K;
        dst[idx] = f2bf(src[(size_t)k * N + n]);
    }
}

// ---------------------------------------------------------------------------
// K3: fused per-2-batch pipeline, 30.7 KB LDS -> 5 blocks/CU (20 waves).
// Agg transpose is done fully in-register via __shfl (no YsT buffer):
// lane(kgrp,l15) builds the B-fragment Y[kgrp*8+t][ncol] from the j-quads
// of source lanes ((kgrp&1)*32+l15) and +16, selecting register p[m],
// m = (ks*4+kgrp)>>1.
// ---------------------------------------------------------------------------
__global__ __launch_bounds__(256, 5) void fused_kernel(
    const float*  __restrict__ feat,   // (B,19,512) f32
    const ushort* __restrict__ adjbf,  // (B,32,32) bf16
    const ushort* __restrict__ W1T,    // (256,512) bf16 [n][k]
    const ushort* __restrict__ W2T,    // (512,256) bf16 [n][k]
    const float*  __restrict__ b1,
    const float*  __restrict__ b2,
    float* __restrict__ out)           // (B,19,512) f32
{
    __shared__ __align__(16) ushort XHs[MP * 256];   // 24576 B (X half-K / H), swizzled
    __shared__ __align__(16) ushort AdjS[MP * 64];   // 6144 B, block-diag 48x64, swizzled

    const int tid = threadIdx.x;
    const int lane = tid & 63, wvi = tid >> 6;
    const int rowbase = blockIdx.x * MR;
    const int bbase = blockIdx.x * GB;
    const int ncol = wvi * 16 + (lane & 15);
    const int kgrp = lane >> 4;
    const int l15 = lane & 15;
    const int s0 = ((kgrp & 1) << 5) + l15;   // shfl source lane 0
    const int s1 = s0 + 16;                   // shfl source lane 1
    const bool lowg = (kgrp < 2);

    // hoisted biases
    float bv1[4], bv2[8];
#pragma unroll
    for (int c = 0; c < 4; c++) bv1[c] = b1[c * 64 + ncol];
#pragma unroll
    for (int c = 0; c < 8; c++) bv2[c] = b2[c * 64 + ncol];

    // stage block-diagonal adjacency: AdjS[g*19+cc][g*19+r] = A_g[cc][r]
    for (int i = tid; i < MP * 64; i += 256) {
        int row = i >> 6, col = i & 63;
        ushort v = 0;
        if (row < MR) {
            int g = (row >= NBOX) ? 1 : 0;
            int cc = row - g * NBOX;
            int rc = col - g * NBOX;
            if ((unsigned)rc < (unsigned)NBOX)
                v = adjbf[(size_t)(bbase + g) * 1024 + cc * 32 + rc];
        }
        int boff = (row * 128 + col * 2) ^ ((row & 7) << 4);
        *(ushort*)((char*)AdjS + boff) = v;
    }

    // ================= GEMM1: Y1 = X @ W1 (K=512, two halves) =================
    f32x4 acc1[4][3];
#pragma unroll
    for (int c = 0; c < 4; c++)
#pragma unroll
        for (int m = 0; m < 3; m++) acc1[c][m] = (f32x4){0.f, 0.f, 0.f, 0.f};

    for (int kh = 0; kh < 2; kh++) {
        __syncthreads();   // kh=0: AdjS init visible; kh=1: prev-half reads done
        const float* fg = feat + (size_t)rowbase * 512 + kh * 256;
#pragma unroll
        for (int p = 0; p < 12; p++) {           // 48 rows x 64 float4-slots
            int i = tid + p * 256;
            int row = i >> 6, q = i & 63;
            ushort4 h;
            if (i < MR * 64) {
                float4 v = *(const float4*)(fg + (size_t)row * 512 + q * 4);
                h.x = f2bf(v.x); h.y = f2bf(v.y); h.z = f2bf(v.z); h.w = f2bf(v.w);
            } else {
                h.x = 0; h.y = 0; h.z = 0; h.w = 0;   // zero-pad rows 38..47
            }
            int boff = (row * 512 + q * 8) ^ ((row & 7) << 4);
            *(ushort4*)((char*)XHs + boff) = h;
        }
        __syncthreads();

        const ushort* bpb = W1T + (size_t)ncol * 512 + kh * 256 + kgrp * 8;
        short8v br[3][4];
#pragma unroll
        for (int c = 0; c < 4; c++)
            br[0][c] = *(const short8v*)(bpb + (size_t)c * 64 * 512);
#pragma unroll
        for (int c = 0; c < 4; c++)
            br[1][c] = *(const short8v*)(bpb + (size_t)c * 64 * 512 + 32);
#pragma unroll
        for (int ks = 0; ks < 8; ks++) {
            if (ks < 6) {
#pragma unroll
                for (int c = 0; c < 4; c++)
                    br[(ks + 2) % 3][c] =
                        *(const short8v*)(bpb + (size_t)c * 64 * 512 + (ks + 2) * 32);
            }
            short8v a[3];
#pragma unroll
            for (int m = 0; m < 3; m++) {
                int row = m * 16 + l15;
                int boff = (row * 512 + ks * 64 + kgrp * 16) ^ ((row & 7) << 4);
                a[m] = *(const short8v*)((char*)XHs + boff);
            }
#pragma unroll
            for (int c = 0; c < 4; c++)
#pragma unroll
                for (int m = 0; m < 3; m++)
                    acc1[c][m] = __builtin_amdgcn_mfma_f32_16x16x32_bf16(
                        a[m], br[ks % 3][c], acc1[c][m], 0, 0, 0);
        }
    }
    __syncthreads();   // all GEMM1 A-reads done; H may overwrite X region

    // ---- agg1 (shfl transpose, no LDS round-trip): Z = Adj @ Y1 -> H ----
    {
        short8v afr[3][2];
#pragma unroll
        for (int mt = 0; mt < 3; mt++)
#pragma unroll
            for (int ks = 0; ks < 2; ks++) {
                int ar = mt * 16 + l15;
                afr[mt][ks] = *(const short8v*)((char*)AdjS +
                              ((ar * 128 + ks * 64 + kgrp * 16) ^ ((ar & 7) << 4)));
            }
#pragma unroll
        for (int c = 0; c < 4; c++) {
            unsigned p0a = pack2bf(acc1[c][0][0], acc1[c][0][1]);
            unsigned p0b = pack2bf(acc1[c][0][2], acc1[c][0][3]);
            unsigned p1a = pack2bf(acc1[c][1][0], acc1[c][1][1]);
            unsigned p1b = pack2bf(acc1[c][1][2], acc1[c][1][3]);
            unsigned p2a = pack2bf(acc1[c][2][0], acc1[c][2][1]);
            unsigned p2b = pack2bf(acc1[c][2][2], acc1[c][2][3]);
            unsigned A0 = __shfl(p0a, s0), A1 = __shfl(p0b, s0);
            unsigned A2 = __shfl(p0a, s1), A3 = __shfl(p0b, s1);
            unsigned B0 = __shfl(p1a, s0), B1 = __shfl(p1b, s0);
            unsigned B2 = __shfl(p1a, s1), B3 = __shfl(p1b, s1);
            unsigned C0 = __shfl(p2a, s0), C1 = __shfl(p2b, s0);
            unsigned C2 = __shfl(p2a, s1), C3 = __shfl(p2b, s1);
            int4 y0i = lowg ? make_int4(A0, A1, A2, A3) : make_int4(B0, B1, B2, B3);
            int4 y1i = lowg ? make_int4(C0, C1, C2, C3) : make_int4(0, 0, 0, 0);
            short8v yb0 = __builtin_bit_cast(short8v, y0i);
            short8v yb1 = __builtin_bit_cast(short8v, y1i);
            float bv = bv1[c];
#pragma unroll
            for (int mt = 0; mt < 3; mt++) {
                f32x4 o = __builtin_amdgcn_mfma_f32_16x16x32_bf16(
                    afr[mt][0], yb0, (f32x4){0.f, 0.f, 0.f, 0.f}, 0, 0, 0);
                o = __builtin_amdgcn_mfma_f32_16x16x32_bf16(
                    afr[mt][1], yb1, o, 0, 0, 0);
#pragma unroll
                for (int j = 0; j < 4; j++) {
                    int grp = mt * 16 + kgrp * 4 + j;
                    float s = sigm(o[j] + bv);
                    int boff = (grp * 512 + (c * 64 + ncol) * 2) ^ ((grp & 7) << 4);
                    *(ushort*)((char*)XHs + boff) = f2bf(s);   // H (aliased on X)
                }
            }
        }
    }
    __syncthreads();   // H fully built before GEMM2 reads

    // ============ GEMM2 + agg2: two halves of 4 chunks (256 cols) ============
#pragma unroll 1
    for (int half = 0; half < 2; half++) {
        f32x4 acc[4][3];
#pragma unroll
        for (int c = 0; c < 4; c++)
#pragma unroll
            for (int m = 0; m < 3; m++) acc[c][m] = (f32x4){0.f, 0.f, 0.f, 0.f};

        const ushort* bpb = W2T + (size_t)(half * 256 + ncol) * 256 + kgrp * 8;
        short8v br[3][4];
#pragma unroll
        for (int c = 0; c < 4; c++)
            br[0][c] = *(const short8v*)(bpb + (size_t)c * 64 * 256);
#pragma unroll
        for (int c = 0; c < 4; c++)
            br[1][c] = *(const short8v*)(bpb + (size_t)c * 64 * 256 + 32);
#pragma unroll
        for (int ks = 0; ks < 8; ks++) {
            if (ks < 6) {
#pragma unroll
                for (int c = 0; c < 4; c++)
                    br[(ks + 2) % 3][c] =
                        *(const short8v*)(bpb + (size_t)c * 64 * 256 + (ks + 2) * 32);
            }
            short8v a[3];
#pragma unroll
            for (int m = 0; m < 3; m++) {
                int row = m * 16 + l15;
                int boff = (row * 512 + ks * 64 + kgrp * 16) ^ ((row & 7) << 4);
                a[m] = *(const short8v*)((char*)XHs + boff);
            }
#pragma unroll
            for (int c = 0; c < 4; c++)
#pragma unroll
                for (int m = 0; m < 3; m++)
                    acc[c][m] = __builtin_amdgcn_mfma_f32_16x16x32_bf16(
                        a[m], br[ks % 3][c], acc[c][m], 0, 0, 0);
        }

        // agg2 (shfl transpose), direct out stores
        short8v afr[3][2];
#pragma unroll
        for (int mt = 0; mt < 3; mt++)
#pragma unroll
            for (int ks = 0; ks < 2; ks++) {
                int ar = mt * 16 + l15;
                afr[mt][ks] = *(const short8v*)((char*)AdjS +
                              ((ar * 128 + ks * 64 + kgrp * 16) ^ ((ar & 7) << 4)));
            }
#pragma unroll
        for (int c = 0; c < 4; c++) {
            int cg = half * 4 + c;
            unsigned p0a = pack2bf(acc[c][0][0], acc[c][0][1]);
            unsigned p0b = pack2bf(acc[c][0][2], acc[c][0][3]);
            unsigned p1a = pack2bf(acc[c][1][0], acc[c][1][1]);
            unsigned p1b = pack2bf(acc[c][1][2], acc[c][1][3]);
            unsigned p2a = pack2bf(acc[c][2][0], acc[c][2][1]);
            unsigned p2b = pack2bf(acc[c][2][2], acc[c][2][3]);
            unsigned A0 = __shfl(p0a, s0), A1 = __shfl(p0b, s0);
            unsigned A2 = __shfl(p0a, s1), A3 = __shfl(p0b, s1);
            unsigned B0 = __shfl(p1a, s0), B1 = __shfl(p1b, s0);
            unsigned B2 = __shfl(p1a, s1), B3 = __shfl(p1b, s1);
            unsigned C0 = __shfl(p2a, s0), C1 = __shfl(p2b, s0);
            unsigned C2 = __shfl(p2a, s1), C3 = __shfl(p2b, s1);
            int4 y0i = lowg ? make_int4(A0, A1, A2, A3) : make_int4(B0, B1, B2, B3);
            int4 y1i = lowg ? make_int4(C0, C1, C2, C3) : make_int4(0, 0, 0, 0);
            short8v yb0 = __builtin_bit_cast(short8v, y0i);
            short8v yb1 = __builtin_bit_cast(short8v, y1i);
            float bv = bv2[cg];
#pragma unroll
            for (int mt = 0; mt < 3; mt++) {
                f32x4 o = __builtin_amdgcn_mfma_f32_16x16x32_bf16(
                    afr[mt][0], yb0, (f32x4){0.f, 0.f, 0.f, 0.f}, 0, 0, 0);
                o = __builtin_amdgcn_mfma_f32_16x16x32_bf16(
                    afr[mt][1], yb1, o, 0, 0, 0);
#pragma unroll
                for (int j = 0; j < 4; j++) {
                    int grp = mt * 16 + kgrp * 4 + j;
                    if (grp < MR) {
                        float s = sigm(o[j] + bv);
                        out[(size_t)(rowbase + grp) * 512 + cg * 64 + ncol] = s;
                    }
                }
            }
        }
    }
}

extern "C" void kernel_launch(void* const* d_in, const int* in_sizes, int n_in,
                              void* d_out, int out_size, void* d_ws, size_t ws_size,
                              hipStream_t stream) {
    const float* loc  = (const float*)d_in[0];
    const float* feat = (const float*)d_in[1];
    const int*   mask = (const int*)d_in[2];
    const float* past = (const float*)d_in[3];
    const float* W1   = (const float*)d_in[4];
    const float* b1   = (const float*)d_in[5];
    const float* W2   = (const float*)d_in[6];
    const float* b2   = (const float*)d_in[7];

    ushort* adjbf = (ushort*)d_ws;                    // 2048*1024 bf16 = 4 MB
    ushort* W1T   = adjbf + (size_t)BATCH * 1024;     // 256*512 bf16
    ushort* W2T   = W1T + 256 * 512;                  // 512*256 bf16

    adjbf_kernel<<<BATCH, 192, 0, stream>>>(loc, mask, past, adjbf);
    packT_kernel<<<512, 256, 0, stream>>>(W1, W1T, 512, 256);
    packT_kernel<<<256, 256, 0, stream>>>(W2, W2T, 256, 512);

    fused_kernel<<<BATCH / GB, 256, 0, stream>>>(feat, adjbf, W1T, W2T, b1, b2,
                                                 (float*)d_out);
}

// Round 10
// 157.170 us; speedup vs baseline: 1.9355x; 1.9355x over previous
//
#include <hip/hip_runtime.h>
#include <hip/hip_bf16.h>
#include <math.h>

#define NBOX 19
#define NEDGE 171
#define TT 5
#define BATCH 2048
#define GB 2                  // batches per fused block
#define MR (GB * NBOX)        // 38 real rows per block
#define MP 48                 // padded rows (3 M-tiles of 16)

typedef __attribute__((ext_vector_type(8))) short short8v;
typedef __attribute__((ext_vector_type(4))) float f32x4;

// cheap bf16 convert: round-half-up (2 VALU ops vs ~5 for RNE)
static __device__ __forceinline__ ushort f2bf(float f) {
    unsigned int u = __builtin_bit_cast(unsigned int, f);
    return (ushort)((u + 0x8000u) >> 16);
}

static __device__ __forceinline__ float sigm(float x) {
    return __builtin_amdgcn_rcpf(1.0f + __expf(-x));
}

__device__ __forceinline__ int edge_index(int r, int c) {
    return r * (NBOX - 1) - (r * (r - 1)) / 2 + (c - r - 1);
}

// ---------------------------------------------------------------------------
// K1: per-batch normalized adjacency, bf16, padded to 32x32
// ---------------------------------------------------------------------------
__global__ __launch_bounds__(192) void adjbf_kernel(
    const float* __restrict__ loc,
    const int*   __restrict__ mask,
    const float* __restrict__ past,
    ushort* __restrict__ adjbf)
{
    int b = blockIdx.x;
    int tid = threadIdx.x;
    __shared__ float cx[NBOX], cy[NBOX], x0[NBOX], y0[NBOX], ndx[NBOX], ndy[NBOX];
    __shared__ int   mv[NBOX];
    __shared__ float w[NEDGE];
    __shared__ float dinv[NBOX];
    __shared__ float wmin_s, wmax_s;

    if (tid < NBOX) {
        const float* l = loc + ((size_t)b * NBOX + tid) * 5;
        cx[tid] = 0.5f * (l[1] + l[3]);
        cy[tid] = 0.5f * (l[2] + l[4]);
        const float* p0 = past + (((size_t)b * TT + 0) * NBOX + tid) * 6;
        const float* p4 = past + (((size_t)b * TT + (TT - 1)) * NBOX + tid) * 6;
        float cpx0 = (p0[3] - p0[1]) * 1280.0f, cpy0 = (p0[4] - p0[2]) * 720.0f;
        float cpx4 = (p4[3] - p4[1]) * 1280.0f, cpy4 = (p4[4] - p4[2]) * 720.0f;
        float dx = cpx4 - cpx0, dy = cpy4 - cpy0;
        float len = sqrtf(dx * dx + dy * dy);
        if (len == 0.0f) len = 1.0f;
        ndx[tid] = dx / len;
        ndy[tid] = dy / len;
        x0[tid] = cpx0;
        y0[tid] = cpy0;
        mv[tid] = mask[(size_t)b * NBOX + tid];
    }
    __syncthreads();

    float wv = 0.0f;
    if (tid < NEDGE) {
        int rem = tid, rr = 0;
        while (rem >= NBOX - 1 - rr) { rem -= NBOX - 1 - rr; rr++; }
        int r = rr, c = rr + 1 + rem;
        float ddx = cx[r] - cx[c], ddy = cy[r] - cy[c];
        float d = ddx * ddx + ddy * ddy;
        float ax = x0[r] + ndx[r] - x0[c] - ndx[c];
        float ay = y0[r] + ndy[r] - y0[c] - ndy[c];
        float d1 = sqrtf(ax * ax + ay * ay);
        float bx = x0[r] - x0[c], by = y0[r] - y0[c];
        float d2 = sqrtf(bx * bx + by * by);
        float md = d1 - d2;
        wv = expf(-(0.7f * d + 0.3f * md));
        if (!(mv[r] && mv[c])) wv = 0.0f;
        w[tid] = wv;
    }
    __syncthreads();

    if (tid == 0) {
        float mn = w[0], mx = w[0];
        for (int i = 1; i < NEDGE; i++) { mn = fminf(mn, w[i]); mx = fmaxf(mx, w[i]); }
        wmin_s = mn; wmax_s = mx;
    }
    __syncthreads();

    float inv_range = 1.0f / (wmax_s - wmin_s);
    if (tid < NEDGE) w[tid] = (wv - wmin_s) * inv_range;
    __syncthreads();

    if (tid < NBOX) {
        float s = 1.0f;
        for (int rr = 0; rr < tid; rr++) s += w[edge_index(rr, tid)];
        dinv[tid] = 1.0f / sqrtf(s);
    }
    __syncthreads();

    ushort* A = adjbf + (size_t)b * 1024;
    for (int idx = tid; idx < 1024; idx += 192) {
        int r = idx & 31, cc = idx >> 5;
        float v = 0.0f;
        if (r < NBOX && cc < NBOX) {
            if (r == cc) v = dinv[r] * dinv[r];
            else if (r < cc) v = w[edge_index(r, cc)] * dinv[r] * dinv[cc];
        }
        A[idx] = f2bf(v);
    }
}

// ---------------------------------------------------------------------------
// K2: transpose + cvt weights: dst[n*K+k] = bf16(src[k*N+n])
// ---------------------------------------------------------------------------
__global__ void packT_kernel(const float* __restrict__ src, ushort* __restrict__ dst,
                             int K, int N)
{
    int total = K * N;
    for (int idx = blockIdx.x * blockDim.x + threadIdx.x; idx < total;
         idx += gridDim.x * blockDim.x) {
        int n = idx / K, k = idx % K;
        dst[idx] = f2bf(src[(size_t)k * N + n]);
    }
}

// ---------------------------------------------------------------------------
// K3: fused per-2-batch pipeline, 512 threads (8 waves), 46 KB LDS ->
// 3 blocks/CU = 24 waves/CU (6/SIMD). Wave wvi owns cols wvi*16+l15 of each
// 128-col chunk. Agg transpose per-wave in YsT slices (barrier-free).
// ZERO-INIT DISCIPLINE (r9 NaN lesson): any padded slot feeding an MFMA must
// be zeroed — XHs pad rows (38..47) and YsT gr 48..63 are zeroed once at
// start; 0*garbage = NaN otherwise.
// ---------------------------------------------------------------------------
__global__ __launch_bounds__(512, 4) void fused_kernel(
    const float*  __restrict__ feat,   // (B,19,512) f32
    const ushort* __restrict__ adjbf,  // (B,32,32) bf16
    const ushort* __restrict__ W1T,    // (256,512) bf16 [n][k]
    const ushort* __restrict__ W2T,    // (512,256) bf16 [n][k]
    const float*  __restrict__ b1,
    const float*  __restrict__ b2,
    float* __restrict__ out)           // (B,19,512) f32
{
    __shared__ __align__(16) ushort XHs[MP * 256];   // 24576 B (X half-K / H), swizzled
    __shared__ __align__(16) ushort YsT[8 * 1024];   // 16384 B, per-wave 2KB slices
    __shared__ __align__(16) ushort AdjS[MP * 64];   // 6144 B, block-diag 48x64, swizzled

    const int tid = threadIdx.x;
    const int lane = tid & 63, wvi = tid >> 6;       // wvi 0..7
    const int rowbase = blockIdx.x * MR;
    const int bbase = blockIdx.x * GB;
    const int kgrp = lane >> 4;
    const int l15 = lane & 15;
    const int colb = wvi * 16 + l15;                 // 0..127: col within chunk
    const int ytbase = wvi * 2048;                   // per-wave YsT byte base

    // one-time zero of XHs (pad rows must be 0 for GEMM A-reads) and YsT
    // (gr 48..63 slots are read by agg but never written)
#pragma unroll
    for (int p = 0; p < 3; p++)
        ((int4*)XHs)[tid + p * 512] = make_int4(0, 0, 0, 0);
#pragma unroll
    for (int p = 0; p < 2; p++)
        ((int4*)YsT)[tid + p * 512] = make_int4(0, 0, 0, 0);

    // stage block-diagonal adjacency: AdjS[g*19+cc][g*19+r] = A_g[cc][r]
    for (int i = tid; i < MP * 64; i += 512) {
        int row = i >> 6, col = i & 63;
        ushort v = 0;
        if (row < MR) {
            int g = (row >= NBOX) ? 1 : 0;
            int cc = row - g * NBOX;
            int rc = col - g * NBOX;
            if ((unsigned)rc < (unsigned)NBOX)
                v = adjbf[(size_t)(bbase + g) * 1024 + cc * 32 + rc];
        }
        int boff = (row * 128 + col * 2) ^ ((row & 7) << 4);
        *(ushort*)((char*)AdjS + boff) = v;
    }

    // ================= GEMM1: Y1 = X @ W1 (K=512, two halves) =================
    f32x4 acc1[2][3];
#pragma unroll
    for (int c = 0; c < 2; c++)
#pragma unroll
        for (int m = 0; m < 3; m++) acc1[c][m] = (f32x4){0.f, 0.f, 0.f, 0.f};

    for (int kh = 0; kh < 2; kh++) {
        __syncthreads();   // kh=0: zero-init/AdjS visible; kh=1: prev-half reads done
        const float* fg = feat + (size_t)rowbase * 512 + kh * 256;
        // 38 real rows x 64 float4-slots; pad rows stay zero from init
#pragma unroll
        for (int p = 0; p < 5; p++) {
            int i = tid + p * 512;
            if (i < MR * 64) {
                int row = i >> 6, q = i & 63;
                float4 v = *(const float4*)(fg + (size_t)row * 512 + q * 4);
                ushort4 h;
                h.x = f2bf(v.x); h.y = f2bf(v.y); h.z = f2bf(v.z); h.w = f2bf(v.w);
                int boff = (row * 512 + q * 8) ^ ((row & 7) << 4);
                *(ushort4*)((char*)XHs + boff) = h;
            }
        }
        __syncthreads();

        const ushort* bp0 = W1T + (size_t)colb * 512 + kh * 256 + kgrp * 8;
        const ushort* bp1 = bp0 + (size_t)128 * 512;
        short8v br[2][2];
        br[0][0] = *(const short8v*)(bp0);
        br[0][1] = *(const short8v*)(bp1);
#pragma unroll
        for (int ks = 0; ks < 8; ks++) {
            if (ks < 7) {
                br[(ks + 1) & 1][0] = *(const short8v*)(bp0 + (ks + 1) * 32);
                br[(ks + 1) & 1][1] = *(const short8v*)(bp1 + (ks + 1) * 32);
            }
            short8v a[3];
#pragma unroll
            for (int m = 0; m < 3; m++) {
                int row = m * 16 + l15;
                int boff = (row * 512 + ks * 64 + kgrp * 16) ^ ((row & 7) << 4);
                a[m] = *(const short8v*)((char*)XHs + boff);
            }
#pragma unroll
            for (int c = 0; c < 2; c++)
#pragma unroll
                for (int m = 0; m < 3; m++)
                    acc1[c][m] = __builtin_amdgcn_mfma_f32_16x16x32_bf16(
                        a[m], br[ks & 1][c], acc1[c][m], 0, 0, 0);
        }
    }
    __syncthreads();   // all GEMM1 A-reads done; H may overwrite X region

    // ---- agg1 (barrier-free, per-wave YsT slice): Z = Adj @ Y1 -> H ----
#pragma unroll
    for (int c = 0; c < 2; c++) {
        int colg = c * 128 + colb;
#pragma unroll
        for (int m = 0; m < 3; m++) {
            int gr0 = m * 16 + kgrp * 4;
            ushort4 hq;
            hq.x = f2bf(acc1[c][m][0]); hq.y = f2bf(acc1[c][m][1]);
            hq.z = f2bf(acc1[c][m][2]); hq.w = f2bf(acc1[c][m][3]);
            int boff = ytbase + ((l15 * 128 + gr0 * 2) ^ ((l15 & 7) << 4));
            *(ushort4*)((char*)YsT + boff) = hq;
        }
        // same-wave LDS dep: compiler inserts lgkmcnt wait
        short8v yb[2];
#pragma unroll
        for (int ks = 0; ks < 2; ks++)
            yb[ks] = *(const short8v*)((char*)YsT + ytbase +
                     ((l15 * 128 + ks * 64 + kgrp * 16) ^ ((l15 & 7) << 4)));
        float bv = b1[colg];
#pragma unroll
        for (int mt = 0; mt < 3; mt++) {
            f32x4 o = (f32x4){0.f, 0.f, 0.f, 0.f};
#pragma unroll
            for (int ks = 0; ks < 2; ks++) {
                int ar = mt * 16 + l15;
                short8v af = *(const short8v*)((char*)AdjS +
                             ((ar * 128 + ks * 64 + kgrp * 16) ^ ((ar & 7) << 4)));
                o = __builtin_amdgcn_mfma_f32_16x16x32_bf16(af, yb[ks], o, 0, 0, 0);
            }
#pragma unroll
            for (int j = 0; j < 4; j++) {
                int grp = mt * 16 + kgrp * 4 + j;
                float s = sigm(o[j] + bv);
                int boff = (grp * 512 + colg * 2) ^ ((grp & 7) << 4);
                *(ushort*)((char*)XHs + boff) = f2bf(s);   // H (aliased on X)
            }
        }
    }
    __syncthreads();   // H fully built before GEMM2 reads

    // ============ GEMM2 + agg2: two halves of 2 chunks (256 cols) ============
#pragma unroll 1
    for (int half = 0; half < 2; half++) {
        f32x4 acc[2][3];
#pragma unroll
        for (int c = 0; c < 2; c++)
#pragma unroll
            for (int m = 0; m < 3; m++) acc[c][m] = (f32x4){0.f, 0.f, 0.f, 0.f};

        const ushort* bp0 = W2T + (size_t)(half * 256 + colb) * 256 + kgrp * 8;
        const ushort* bp1 = bp0 + (size_t)128 * 256;
        short8v br[2][2];
        br[0][0] = *(const short8v*)(bp0);
        br[0][1] = *(const short8v*)(bp1);
#pragma unroll
        for (int ks = 0; ks < 8; ks++) {
            if (ks < 7) {
                br[(ks + 1) & 1][0] = *(const short8v*)(bp0 + (ks + 1) * 32);
                br[(ks + 1) & 1][1] = *(const short8v*)(bp1 + (ks + 1) * 32);
            }
            short8v a[3];
#pragma unroll
            for (int m = 0; m < 3; m++) {
                int row = m * 16 + l15;
                int boff = (row * 512 + ks * 64 + kgrp * 16) ^ ((row & 7) << 4);
                a[m] = *(const short8v*)((char*)XHs + boff);
            }
#pragma unroll
            for (int c = 0; c < 2; c++)
#pragma unroll
                for (int m = 0; m < 3; m++)
                    acc[c][m] = __builtin_amdgcn_mfma_f32_16x16x32_bf16(
                        a[m], br[ks & 1][c], acc[c][m], 0, 0, 0);
        }

        // agg2 (barrier-free, per-wave YsT), direct out stores
#pragma unroll
        for (int c = 0; c < 2; c++) {
            int colg2 = half * 256 + c * 128 + colb;
#pragma unroll
            for (int m = 0; m < 3; m++) {
                int gr0 = m * 16 + kgrp * 4;
                ushort4 hq;
                hq.x = f2bf(acc[c][m][0]); hq.y = f2bf(acc[c][m][1]);
                hq.z = f2bf(acc[c][m][2]); hq.w = f2bf(acc[c][m][3]);
                int boff = ytbase + ((l15 * 128 + gr0 * 2) ^ ((l15 & 7) << 4));
                *(ushort4*)((char*)YsT + boff) = hq;
            }
            short8v yb[2];
#pragma unroll
            for (int ks = 0; ks < 2; ks++)
                yb[ks] = *(const short8v*)((char*)YsT + ytbase +
                         ((l15 * 128 + ks * 64 + kgrp * 16) ^ ((l15 & 7) << 4)));
            float bv = b2[colg2];
#pragma unroll
            for (int mt = 0; mt < 3; mt++) {
                f32x4 o = (f32x4){0.f, 0.f, 0.f, 0.f};
#pragma unroll
                for (int ks = 0; ks < 2; ks++) {
                    int ar = mt * 16 + l15;
                    short8v af = *(const short8v*)((char*)AdjS +
                                 ((ar * 128 + ks * 64 + kgrp * 16) ^ ((ar & 7) << 4)));
                    o = __builtin_amdgcn_mfma_f32_16x16x32_bf16(af, yb[ks], o, 0, 0, 0);
                }
#pragma unroll
                for (int j = 0; j < 4; j++) {
                    int grp = mt * 16 + kgrp * 4 + j;
                    if (grp < MR) {
                        float s = sigm(o[j] + bv);
                        out[(size_t)(rowbase + grp) * 512 + colg2] = s;
                    }
                }
            }
        }
    }
}

extern "C" void kernel_launch(void* const* d_in, const int* in_sizes, int n_in,
                              void* d_out, int out_size, void* d_ws, size_t ws_size,
                              hipStream_t stream) {
    const float* loc  = (const float*)d_in[0];
    const float* feat = (const float*)d_in[1];
    const int*   mask = (const int*)d_in[2];
    const float* past = (const float*)d_in[3];
    const float* W1   = (const float*)d_in[4];
    const float* b1   = (const float*)d_in[5];
    const float* W2   = (const float*)d_in[6];
    const float* b2   = (const float*)d_in[7];

    ushort* adjbf = (ushort*)d_ws;                    // 2048*1024 bf16 = 4 MB
    ushort* W1T   = adjbf + (size_t)BATCH * 1024;     // 256*512 bf16
    ushort* W2T   = W1T + 256 * 512;                  // 512*256 bf16

    adjbf_kernel<<<BATCH, 192, 0, stream>>>(loc, mask, past, adjbf);
    packT_kernel<<<512, 256, 0, stream>>>(W1, W1T, 512, 256);
    packT_kernel<<<256, 256, 0, stream>>>(W2, W2T, 256, 512);

    fused_kernel<<<BATCH / GB, 512, 0, stream>>>(feat, adjbf, W1T, W2T, b1, b2,
                                                 (float*)d_out);
}

// Round 11
// 134.761 us; speedup vs baseline: 2.2573x; 1.1663x over previous
//
#include <hip/hip_runtime.h>
#include <hip/hip_bf16.h>
#include <math.h>

#define NBOX 19
#define NEDGE 171
#define TT 5
#define BATCH 2048
#define GB 2                  // batches per fused block
#define MR (GB * NBOX)        // 38 real rows per block
#define MP 48                 // padded rows (3 M-tiles of 16)

typedef __attribute__((ext_vector_type(8))) short short8v;
typedef __attribute__((ext_vector_type(4))) float f32x4;

// cheap bf16 convert: round-half-up (2 VALU ops vs ~5 for RNE)
static __device__ __forceinline__ ushort f2bf(float f) {
    unsigned int u = __builtin_bit_cast(unsigned int, f);
    return (ushort)((u + 0x8000u) >> 16);
}

static __device__ __forceinline__ float sigm(float x) {
    return __builtin_amdgcn_rcpf(1.0f + __expf(-x));
}

__device__ __forceinline__ int edge_index(int r, int c) {
    return r * (NBOX - 1) - (r * (r - 1)) / 2 + (c - r - 1);
}

// ---------------------------------------------------------------------------
// K1: per-batch edge weights -> PRE-SWIZZLED block-diag 48x64 bf16 pair image.
// Pair p = batches (2p, 2p+1). Batch g writes its 24 rows (19 real + 5 pad)
// of the image as 192 aligned int4 stores. Swizzle matches fused reads:
// boff = (row*128 + col*2) ^ ((row&7)<<4).
// ---------------------------------------------------------------------------
__global__ __launch_bounds__(192) void adjpair_kernel(
    const float* __restrict__ loc,
    const int*   __restrict__ mask,
    const float* __restrict__ past,
    ushort* __restrict__ pairimg)      // (B/2, 48*64) bf16, swizzled
{
    int b = blockIdx.x;
    int p = b >> 1, g = b & 1;
    int tid = threadIdx.x;
    __shared__ float cx[NBOX], cy[NBOX], x0[NBOX], y0[NBOX], ndx[NBOX], ndy[NBOX];
    __shared__ int   mv[NBOX];
    __shared__ float w[NEDGE];
    __shared__ float dinv[NBOX];
    __shared__ float rmn[3], rmx[3];

    if (tid < NBOX) {
        const float* l = loc + ((size_t)b * NBOX + tid) * 5;
        cx[tid] = 0.5f * (l[1] + l[3]);
        cy[tid] = 0.5f * (l[2] + l[4]);
        const float* p0 = past + (((size_t)b * TT + 0) * NBOX + tid) * 6;
        const float* p4 = past + (((size_t)b * TT + (TT - 1)) * NBOX + tid) * 6;
        float cpx0 = (p0[3] - p0[1]) * 1280.0f, cpy0 = (p0[4] - p0[2]) * 720.0f;
        float cpx4 = (p4[3] - p4[1]) * 1280.0f, cpy4 = (p4[4] - p4[2]) * 720.0f;
        float dx = cpx4 - cpx0, dy = cpy4 - cpy0;
        float len = sqrtf(dx * dx + dy * dy);
        if (len == 0.0f) len = 1.0f;
        ndx[tid] = dx / len;
        ndy[tid] = dy / len;
        x0[tid] = cpx0;
        y0[tid] = cpy0;
        mv[tid] = mask[(size_t)b * NBOX + tid];
    }
    __syncthreads();

    float wv = 0.0f;
    if (tid < NEDGE) {
        int rem = tid, rr = 0;
        while (rem >= NBOX - 1 - rr) { rem -= NBOX - 1 - rr; rr++; }
        int r = rr, c = rr + 1 + rem;
        float ddx = cx[r] - cx[c], ddy = cy[r] - cy[c];
        float d = ddx * ddx + ddy * ddy;
        float ax = x0[r] + ndx[r] - x0[c] - ndx[c];
        float ay = y0[r] + ndy[r] - y0[c] - ndy[c];
        float d1 = sqrtf(ax * ax + ay * ay);
        float bx = x0[r] - x0[c], by = y0[r] - y0[c];
        float d2 = sqrtf(bx * bx + by * by);
        float md = d1 - d2;
        wv = expf(-(0.7f * d + 0.3f * md));
        if (!(mv[r] && mv[c])) wv = 0.0f;
    }

    // parallel min/max over the 171 edge weights (3-wave shfl reduce)
    float lmn = (tid < NEDGE) ? wv : INFINITY;
    float lmx = (tid < NEDGE) ? wv : -INFINITY;
#pragma unroll
    for (int o = 32; o; o >>= 1) {
        lmn = fminf(lmn, __shfl_xor(lmn, o));
        lmx = fmaxf(lmx, __shfl_xor(lmx, o));
    }
    if ((tid & 63) == 0) { rmn[tid >> 6] = lmn; rmx[tid >> 6] = lmx; }
    __syncthreads();
    float mn = fminf(rmn[0], fminf(rmn[1], rmn[2]));
    float mx = fmaxf(rmx[0], fmaxf(rmx[1], rmx[2]));
    float inv_range = 1.0f / (mx - mn);
    if (tid < NEDGE) w[tid] = (wv - mn) * inv_range;
    __syncthreads();

    if (tid < NBOX) {
        float s = 1.0f;
        for (int rr = 0; rr < tid; rr++) s += w[edge_index(rr, tid)];
        dinv[tid] = 1.0f / sqrtf(s);
    }
    __syncthreads();

    // write 24 rows x 8 int4-chunks of the pair image (batch g's half)
    {
        int row_local = tid >> 3, chunk = tid & 7;
        int row = (g == 0)
            ? (row_local < NBOX ? row_local : NBOX + row_local)        // 0..18, 38..42
            : (row_local < NBOX ? NBOX + row_local : 24 + row_local);  // 19..37, 43..47
        ushort vals[8];
#pragma unroll
        for (int i = 0; i < 8; i++) {
            int col = chunk * 8 + i;
            int rc = col - g * NBOX;
            float v = 0.0f;
            if (row_local < NBOX && rc >= 0 && rc < NBOX) {
                int cc = row_local;
                if (rc == cc) v = dinv[cc] * dinv[cc];
                else if (rc < cc) v = w[edge_index(rc, cc)] * dinv[rc] * dinv[cc];
            }
            vals[i] = f2bf(v);
        }
        int boff = (row * 128 + chunk * 16) ^ ((row & 7) << 4);
        *(int4*)((char*)pairimg + (size_t)p * 6144 + boff) = *(int4*)vals;
    }
}

// ---------------------------------------------------------------------------
// K2: transpose + cvt both weights in one launch:
// dst[n*K+k] = bf16(src[k*N+n]); idx < 131072 -> W1, else W2.
// ---------------------------------------------------------------------------
__global__ void packT2_kernel(const float* __restrict__ W1,
                              const float* __restrict__ W2,
                              ushort* __restrict__ W1T,
                              ushort* __restrict__ W2T)
{
    int idx = blockIdx.x * blockDim.x + threadIdx.x;   // grid covers 262144
    if (idx < 131072) {
        int n = idx / 512, k = idx % 512;               // W1: K=512, N=256
        W1T[idx] = f2bf(W1[(size_t)k * 256 + n]);
    } else {
        int j = idx - 131072;
        int n = j / 256, k = j % 256;                   // W2: K=256, N=512
        W2T[j] = f2bf(W2[(size_t)k * 512 + n]);
    }
}

// ---------------------------------------------------------------------------
// K3: fused per-2-batch pipeline (r7 structure), 38.9 KB LDS -> 4 blocks/CU.
// AdjS staged by linear int4 copy of the pre-swizzled pair image.
// s_setprio(1) around MFMA clusters (4 independent blocks/CU give the
// phase diversity T5 needs).
// ---------------------------------------------------------------------------
__global__ __launch_bounds__(256, 4) void fused_kernel(
    const float*  __restrict__ feat,    // (B,19,512) f32
    const ushort* __restrict__ pairimg, // (B/2,48*64) bf16 swizzled
    const ushort* __restrict__ W1T,     // (256,512) bf16 [n][k]
    const ushort* __restrict__ W2T,     // (512,256) bf16 [n][k]
    const float*  __restrict__ b1,
    const float*  __restrict__ b2,
    float* __restrict__ out)            // (B,19,512) f32
{
    __shared__ __align__(16) ushort XHs[MP * 256];   // 24576 B (X half-K / H), swizzled
    __shared__ __align__(16) ushort YsT[64 * 64];    // 8192 B, [ncol][gr], per-wave slices
    __shared__ __align__(16) ushort AdjS[MP * 64];   // 6144 B, block-diag 48x64, swizzled

    const int tid = threadIdx.x;
    const int lane = tid & 63, wvi = tid >> 6;
    const int rowbase = blockIdx.x * MR;
    const int ncol = wvi * 16 + (lane & 15);
    const int kgrp = lane >> 4;
    const int l15 = lane & 15;

    // zero YsT (rows >= 48 slots are read by agg but never written)
#pragma unroll
    for (int p = 0; p < 2; p++)
        ((int4*)YsT)[tid + p * 256] = make_int4(0, 0, 0, 0);

    // stage pre-swizzled pair image: 384 int4 linear copy
    {
        const int4* src = (const int4*)((const char*)pairimg + (size_t)blockIdx.x * 6144);
        ((int4*)AdjS)[tid] = src[tid];
        if (tid < 128) ((int4*)AdjS)[tid + 256] = src[tid + 256];
    }

    // ================= GEMM1: Y1 = X @ W1 (K=512, two halves) =================
    f32x4 acc1[4][3];
#pragma unroll
    for (int c = 0; c < 4; c++)
#pragma unroll
        for (int m = 0; m < 3; m++) acc1[c][m] = (f32x4){0.f, 0.f, 0.f, 0.f};

    for (int kh = 0; kh < 2; kh++) {
        __syncthreads();   // kh=0: YsT/AdjS init visible; kh=1: prev-half reads done
        const float* fg = feat + (size_t)rowbase * 512 + kh * 256;
#pragma unroll
        for (int p = 0; p < 12; p++) {           // 48 rows x 64 float4-slots
            int i = tid + p * 256;
            int row = i >> 6, q = i & 63;
            ushort4 h;
            if (i < MR * 64) {
                float4 v = *(const float4*)(fg + (size_t)row * 512 + q * 4);
                h.x = f2bf(v.x); h.y = f2bf(v.y); h.z = f2bf(v.z); h.w = f2bf(v.w);
            } else {
                h.x = 0; h.y = 0; h.z = 0; h.w = 0;   // zero-pad rows 38..47
            }
            int boff = (row * 512 + q * 8) ^ ((row & 7) << 4);
            *(ushort4*)((char*)XHs + boff) = h;
        }
        __syncthreads();

        const ushort* bpb = W1T + (size_t)ncol * 512 + kh * 256 + kgrp * 8;
        short8v br[3][4];
#pragma unroll
        for (int c = 0; c < 4; c++)
            br[0][c] = *(const short8v*)(bpb + (size_t)c * 64 * 512);
#pragma unroll
        for (int c = 0; c < 4; c++)
            br[1][c] = *(const short8v*)(bpb + (size_t)c * 64 * 512 + 32);
#pragma unroll
        for (int ks = 0; ks < 8; ks++) {
            if (ks < 6) {
#pragma unroll
                for (int c = 0; c < 4; c++)
                    br[(ks + 2) % 3][c] =
                        *(const short8v*)(bpb + (size_t)c * 64 * 512 + (ks + 2) * 32);
            }
            short8v a[3];
#pragma unroll
            for (int m = 0; m < 3; m++) {
                int row = m * 16 + l15;
                int boff = (row * 512 + ks * 64 + kgrp * 16) ^ ((row & 7) << 4);
                a[m] = *(const short8v*)((char*)XHs + boff);
            }
            __builtin_amdgcn_s_setprio(1);
#pragma unroll
            for (int c = 0; c < 4; c++)
#pragma unroll
                for (int m = 0; m < 3; m++)
                    acc1[c][m] = __builtin_amdgcn_mfma_f32_16x16x32_bf16(
                        a[m], br[ks % 3][c], acc1[c][m], 0, 0, 0);
            __builtin_amdgcn_s_setprio(0);
        }
    }
    __syncthreads();   // all GEMM1 A-reads done; H may overwrite X region

    // ---- agg1 (barrier-free): per chunk: YsT <- bf16(Y1), aggMFMA -> H ----
#pragma unroll
    for (int c = 0; c < 4; c++) {
#pragma unroll
        for (int m = 0; m < 3; m++) {
            int gr0 = m * 16 + kgrp * 4;
            ushort4 hq;
            hq.x = f2bf(acc1[c][m][0]); hq.y = f2bf(acc1[c][m][1]);
            hq.z = f2bf(acc1[c][m][2]); hq.w = f2bf(acc1[c][m][3]);
            int boff = (ncol * 128 + gr0 * 2) ^ ((ncol & 7) << 4);
            *(ushort4*)((char*)YsT + boff) = hq;
        }
        // same-wave LDS dependency only: compiler inserts lgkmcnt wait
        short8v yb[2];
#pragma unroll
        for (int ks = 0; ks < 2; ks++)
            yb[ks] = *(const short8v*)((char*)YsT +
                     ((ncol * 128 + ks * 64 + kgrp * 16) ^ ((ncol & 7) << 4)));
        float bv = b1[c * 64 + ncol];
#pragma unroll
        for (int mt = 0; mt < 3; mt++) {
            f32x4 o = (f32x4){0.f, 0.f, 0.f, 0.f};
#pragma unroll
            for (int ks = 0; ks < 2; ks++) {
                int ar = mt * 16 + l15;
                short8v af = *(const short8v*)((char*)AdjS +
                             ((ar * 128 + ks * 64 + kgrp * 16) ^ ((ar & 7) << 4)));
                o = __builtin_amdgcn_mfma_f32_16x16x32_bf16(af, yb[ks], o, 0, 0, 0);
            }
#pragma unroll
            for (int j = 0; j < 4; j++) {
                int grp = mt * 16 + kgrp * 4 + j;
                float s = sigm(o[j] + bv);
                int boff = (grp * 512 + (c * 64 + ncol) * 2) ^ ((grp & 7) << 4);
                *(ushort*)((char*)XHs + boff) = f2bf(s);   // H (aliased on X)
            }
        }
    }
    __syncthreads();   // H fully built before GEMM2 reads

    // ============ GEMM2 + agg2: two halves of 4 chunks (256 cols) ============
#pragma unroll 1
    for (int half = 0; half < 2; half++) {
        f32x4 acc[4][3];
#pragma unroll
        for (int c = 0; c < 4; c++)
#pragma unroll
            for (int m = 0; m < 3; m++) acc[c][m] = (f32x4){0.f, 0.f, 0.f, 0.f};

        const ushort* bpb = W2T + (size_t)(half * 256 + ncol) * 256 + kgrp * 8;
        short8v br[3][4];
#pragma unroll
        for (int c = 0; c < 4; c++)
            br[0][c] = *(const short8v*)(bpb + (size_t)c * 64 * 256);
#pragma unroll
        for (int c = 0; c < 4; c++)
            br[1][c] = *(const short8v*)(bpb + (size_t)c * 64 * 256 + 32);
#pragma unroll
        for (int ks = 0; ks < 8; ks++) {
            if (ks < 6) {
#pragma unroll
                for (int c = 0; c < 4; c++)
                    br[(ks + 2) % 3][c] =
                        *(const short8v*)(bpb + (size_t)c * 64 * 256 + (ks + 2) * 32);
            }
            short8v a[3];
#pragma unroll
            for (int m = 0; m < 3; m++) {
                int row = m * 16 + l15;
                int boff = (row * 512 + ks * 64 + kgrp * 16) ^ ((row & 7) << 4);
                a[m] = *(const short8v*)((char*)XHs + boff);
            }
            __builtin_amdgcn_s_setprio(1);
#pragma unroll
            for (int c = 0; c < 4; c++)
#pragma unroll
                for (int m = 0; m < 3; m++)
                    acc[c][m] = __builtin_amdgcn_mfma_f32_16x16x32_bf16(
                        a[m], br[ks % 3][c], acc[c][m], 0, 0, 0);
            __builtin_amdgcn_s_setprio(0);
        }

        // agg2 (barrier-free, per-wave YsT), direct out stores
#pragma unroll
        for (int c = 0; c < 4; c++) {
            int cg = half * 4 + c;
#pragma unroll
            for (int m = 0; m < 3; m++) {
                int gr0 = m * 16 + kgrp * 4;
                ushort4 hq;
                hq.x = f2bf(acc[c][m][0]); hq.y = f2bf(acc[c][m][1]);
                hq.z = f2bf(acc[c][m][2]); hq.w = f2bf(acc[c][m][3]);
                int boff = (ncol * 128 + gr0 * 2) ^ ((ncol & 7) << 4);
                *(ushort4*)((char*)YsT + boff) = hq;
            }
            short8v yb[2];
#pragma unroll
            for (int ks = 0; ks < 2; ks++)
                yb[ks] = *(const short8v*)((char*)YsT +
                         ((ncol * 128 + ks * 64 + kgrp * 16) ^ ((ncol & 7) << 4)));
            float bv = b2[cg * 64 + ncol];
#pragma unroll
            for (int mt = 0; mt < 3; mt++) {
                f32x4 o = (f32x4){0.f, 0.f, 0.f, 0.f};
#pragma unroll
                for (int ks = 0; ks < 2; ks++) {
                    int ar = mt * 16 + l15;
                    short8v af = *(const short8v*)((char*)AdjS +
                                 ((ar * 128 + ks * 64 + kgrp * 16) ^ ((ar & 7) << 4)));
                    o = __builtin_amdgcn_mfma_f32_16x16x32_bf16(af, yb[ks], o, 0, 0, 0);
                }
#pragma unroll
                for (int j = 0; j < 4; j++) {
                    int grp = mt * 16 + kgrp * 4 + j;
                    if (grp < MR) {
                        float s = sigm(o[j] + bv);
                        out[(size_t)(rowbase + grp) * 512 + cg * 64 + ncol] = s;
                    }
                }
            }
        }
    }
}

extern "C" void kernel_launch(void* const* d_in, const int* in_sizes, int n_in,
                              void* d_out, int out_size, void* d_ws, size_t ws_size,
                              hipStream_t stream) {
    const float* loc  = (const float*)d_in[0];
    const float* feat = (const float*)d_in[1];
    const int*   mask = (const int*)d_in[2];
    const float* past = (const float*)d_in[3];
    const float* W1   = (const float*)d_in[4];
    const float* b1   = (const float*)d_in[5];
    const float* W2   = (const float*)d_in[6];
    const float* b2   = (const float*)d_in[7];

    ushort* pairimg = (ushort*)d_ws;                       // 1024*3072 bf16 = 6 MB
    ushort* W1T     = pairimg + (size_t)(BATCH / 2) * 3072; // 256*512 bf16
    ushort* W2T     = W1T + 256 * 512;                      // 512*256 bf16

    adjpair_kernel<<<BATCH, 192, 0, stream>>>(loc, mask, past, pairimg);
    packT2_kernel<<<1024, 256, 0, stream>>>(W1, W2, W1T, W2T);

    fused_kernel<<<BATCH / GB, 256, 0, stream>>>(feat, pairimg, W1T, W2T, b1, b2,
                                                 (float*)d_out);
}

// Round 12
// 106.052 us; speedup vs baseline: 2.8684x; 1.2707x over previous
//
#include <hip/hip_runtime.h>
#include <hip/hip_bf16.h>
#include <math.h>

#define NBOX 19
#define NEDGE 171
#define TT 5
#define BATCH 2048
#define GB 2                  // batches per fused block
#define MR (GB * NBOX)        // 38 real rows per block
#define MP 48                 // padded rows (3 M-tiles of 16)

typedef __attribute__((ext_vector_type(8))) short short8v;
typedef __attribute__((ext_vector_type(4))) float f32x4;

// cheap bf16 convert: round-half-up (2 VALU ops vs ~5 for RNE)
static __device__ __forceinline__ ushort f2bf(float f) {
    unsigned int u = __builtin_bit_cast(unsigned int, f);
    return (ushort)((u + 0x8000u) >> 16);
}

static __device__ __forceinline__ float sigm(float x) {
    return __builtin_amdgcn_rcpf(1.0f + __expf(-x));
}

__device__ __forceinline__ int edge_index(int r, int c) {
    return r * (NBOX - 1) - (r * (r - 1)) / 2 + (c - r - 1);
}

// ---------------------------------------------------------------------------
// K1: per-batch edge weights -> PRE-SWIZZLED block-diag 48x64 bf16 pair image.
// Pair p = batches (2p, 2p+1). Batch g writes its 24 rows (19 real + 5 pad)
// of the image as 192 aligned int4 stores. Swizzle matches fused reads:
// boff = (row*128 + col*2) ^ ((row&7)<<4).   [passed in r11]
// ---------------------------------------------------------------------------
__global__ __launch_bounds__(192) void adjpair_kernel(
    const float* __restrict__ loc,
    const int*   __restrict__ mask,
    const float* __restrict__ past,
    ushort* __restrict__ pairimg)      // (B/2, 48*64) bf16, swizzled
{
    int b = blockIdx.x;
    int p = b >> 1, g = b & 1;
    int tid = threadIdx.x;
    __shared__ float cx[NBOX], cy[NBOX], x0[NBOX], y0[NBOX], ndx[NBOX], ndy[NBOX];
    __shared__ int   mv[NBOX];
    __shared__ float w[NEDGE];
    __shared__ float dinv[NBOX];
    __shared__ float rmn[3], rmx[3];

    if (tid < NBOX) {
        const float* l = loc + ((size_t)b * NBOX + tid) * 5;
        cx[tid] = 0.5f * (l[1] + l[3]);
        cy[tid] = 0.5f * (l[2] + l[4]);
        const float* p0 = past + (((size_t)b * TT + 0) * NBOX + tid) * 6;
        const float* p4 = past + (((size_t)b * TT + (TT - 1)) * NBOX + tid) * 6;
        float cpx0 = (p0[3] - p0[1]) * 1280.0f, cpy0 = (p0[4] - p0[2]) * 720.0f;
        float cpx4 = (p4[3] - p4[1]) * 1280.0f, cpy4 = (p4[4] - p4[2]) * 720.0f;
        float dx = cpx4 - cpx0, dy = cpy4 - cpy0;
        float len = sqrtf(dx * dx + dy * dy);
        if (len == 0.0f) len = 1.0f;
        ndx[tid] = dx / len;
        ndy[tid] = dy / len;
        x0[tid] = cpx0;
        y0[tid] = cpy0;
        mv[tid] = mask[(size_t)b * NBOX + tid];
    }
    __syncthreads();

    float wv = 0.0f;
    if (tid < NEDGE) {
        int rem = tid, rr = 0;
        while (rem >= NBOX - 1 - rr) { rem -= NBOX - 1 - rr; rr++; }
        int r = rr, c = rr + 1 + rem;
        float ddx = cx[r] - cx[c], ddy = cy[r] - cy[c];
        float d = ddx * ddx + ddy * ddy;
        float ax = x0[r] + ndx[r] - x0[c] - ndx[c];
        float ay = y0[r] + ndy[r] - y0[c] - ndy[c];
        float d1 = sqrtf(ax * ax + ay * ay);
        float bx = x0[r] - x0[c], by = y0[r] - y0[c];
        float d2 = sqrtf(bx * bx + by * by);
        float md = d1 - d2;
        wv = expf(-(0.7f * d + 0.3f * md));
        if (!(mv[r] && mv[c])) wv = 0.0f;
    }

    // parallel min/max over the 171 edge weights (3-wave shfl reduce)
    float lmn = (tid < NEDGE) ? wv : INFINITY;
    float lmx = (tid < NEDGE) ? wv : -INFINITY;
#pragma unroll
    for (int o = 32; o; o >>= 1) {
        lmn = fminf(lmn, __shfl_xor(lmn, o));
        lmx = fmaxf(lmx, __shfl_xor(lmx, o));
    }
    if ((tid & 63) == 0) { rmn[tid >> 6] = lmn; rmx[tid >> 6] = lmx; }
    __syncthreads();
    float mn = fminf(rmn[0], fminf(rmn[1], rmn[2]));
    float mx = fmaxf(rmx[0], fmaxf(rmx[1], rmx[2]));
    float inv_range = 1.0f / (mx - mn);
    if (tid < NEDGE) w[tid] = (wv - mn) * inv_range;
    __syncthreads();

    if (tid < NBOX) {
        float s = 1.0f;
        for (int rr = 0; rr < tid; rr++) s += w[edge_index(rr, tid)];
        dinv[tid] = 1.0f / sqrtf(s);
    }
    __syncthreads();

    // write 24 rows x 8 int4-chunks of the pair image (batch g's half)
    {
        int row_local = tid >> 3, chunk = tid & 7;
        int row = (g == 0)
            ? (row_local < NBOX ? row_local : NBOX + row_local)        // 0..18, 38..42
            : (row_local < NBOX ? NBOX + row_local : 24 + row_local);  // 19..37, 43..47
        ushort vals[8];
#pragma unroll
        for (int i = 0; i < 8; i++) {
            int col = chunk * 8 + i;
            int rc = col - g * NBOX;
            float v = 0.0f;
            if (row_local < NBOX && rc >= 0 && rc < NBOX) {
                int cc = row_local;
                if (rc == cc) v = dinv[cc] * dinv[cc];
                else if (rc < cc) v = w[edge_index(rc, cc)] * dinv[rc] * dinv[cc];
            }
            vals[i] = f2bf(v);
        }
        int boff = (row * 128 + chunk * 16) ^ ((row & 7) << 4);
        *(int4*)((char*)pairimg + (size_t)p * 6144 + boff) = *(int4*)vals;
    }
}

// ---------------------------------------------------------------------------
// K2: transpose + cvt both weights in one launch:
// dst[n*K+k] = bf16(src[k*N+n]); idx < 131072 -> W1, else W2.
// ---------------------------------------------------------------------------
__global__ void packT2_kernel(const float* __restrict__ W1,
                              const float* __restrict__ W2,
                              ushort* __restrict__ W1T,
                              ushort* __restrict__ W2T)
{
    int idx = blockIdx.x * blockDim.x + threadIdx.x;   // grid covers 262144
    if (idx < 131072) {
        int n = idx / 512, k = idx % 512;               // W1: K=512, N=256
        W1T[idx] = f2bf(W1[(size_t)k * 256 + n]);
    } else {
        int j = idx - 131072;
        int n = j / 256, k = j % 256;                   // W2: K=256, N=512
        W2T[j] = f2bf(W2[(size_t)k * 512 + n]);
    }
}

// ---------------------------------------------------------------------------
// K3: fused per-2-batch pipeline (EXACT r7 structure, no setprio).
// 38.9 KB LDS -> 4 blocks/CU. AdjS staged by linear int4 copy of the
// pre-swizzled pair image. B operands: 3-slot register ring.
// ---------------------------------------------------------------------------
__global__ __launch_bounds__(256, 4) void fused_kernel(
    const float*  __restrict__ feat,    // (B,19,512) f32
    const ushort* __restrict__ pairimg, // (B/2,48*64) bf16 swizzled
    const ushort* __restrict__ W1T,     // (256,512) bf16 [n][k]
    const ushort* __restrict__ W2T,     // (512,256) bf16 [n][k]
    const float*  __restrict__ b1,
    const float*  __restrict__ b2,
    float* __restrict__ out)            // (B,19,512) f32
{
    __shared__ __align__(16) ushort XHs[MP * 256];   // 24576 B (X half-K / H), swizzled
    __shared__ __align__(16) ushort YsT[64 * 64];    // 8192 B, [ncol][gr], per-wave slices
    __shared__ __align__(16) ushort AdjS[MP * 64];   // 6144 B, block-diag 48x64, swizzled

    const int tid = threadIdx.x;
    const int lane = tid & 63, wvi = tid >> 6;
    const int rowbase = blockIdx.x * MR;
    const int ncol = wvi * 16 + (lane & 15);
    const int kgrp = lane >> 4;
    const int l15 = lane & 15;

    // zero YsT (rows >= 48 slots are read by agg but never written)
#pragma unroll
    for (int p = 0; p < 2; p++)
        ((int4*)YsT)[tid + p * 256] = make_int4(0, 0, 0, 0);

    // stage pre-swizzled pair image: 384 int4 linear copy
    {
        const int4* src = (const int4*)((const char*)pairimg + (size_t)blockIdx.x * 6144);
        ((int4*)AdjS)[tid] = src[tid];
        if (tid < 128) ((int4*)AdjS)[tid + 256] = src[tid + 256];
    }

    // ================= GEMM1: Y1 = X @ W1 (K=512, two halves) =================
    f32x4 acc1[4][3];
#pragma unroll
    for (int c = 0; c < 4; c++)
#pragma unroll
        for (int m = 0; m < 3; m++) acc1[c][m] = (f32x4){0.f, 0.f, 0.f, 0.f};

    for (int kh = 0; kh < 2; kh++) {
        __syncthreads();   // kh=0: YsT/AdjS init visible; kh=1: prev-half reads done
        const float* fg = feat + (size_t)rowbase * 512 + kh * 256;
#pragma unroll
        for (int p = 0; p < 12; p++) {           // 48 rows x 64 float4-slots
            int i = tid + p * 256;
            int row = i >> 6, q = i & 63;
            ushort4 h;
            if (i < MR * 64) {
                float4 v = *(const float4*)(fg + (size_t)row * 512 + q * 4);
                h.x = f2bf(v.x); h.y = f2bf(v.y); h.z = f2bf(v.z); h.w = f2bf(v.w);
            } else {
                h.x = 0; h.y = 0; h.z = 0; h.w = 0;   // zero-pad rows 38..47
            }
            int boff = (row * 512 + q * 8) ^ ((row & 7) << 4);
            *(ushort4*)((char*)XHs + boff) = h;
        }
        __syncthreads();

        const ushort* bpb = W1T + (size_t)ncol * 512 + kh * 256 + kgrp * 8;
        short8v br[3][4];
#pragma unroll
        for (int c = 0; c < 4; c++)
            br[0][c] = *(const short8v*)(bpb + (size_t)c * 64 * 512);
#pragma unroll
        for (int c = 0; c < 4; c++)
            br[1][c] = *(const short8v*)(bpb + (size_t)c * 64 * 512 + 32);
#pragma unroll
        for (int ks = 0; ks < 8; ks++) {
            if (ks < 6) {
#pragma unroll
                for (int c = 0; c < 4; c++)
                    br[(ks + 2) % 3][c] =
                        *(const short8v*)(bpb + (size_t)c * 64 * 512 + (ks + 2) * 32);
            }
            short8v a[3];
#pragma unroll
            for (int m = 0; m < 3; m++) {
                int row = m * 16 + l15;
                int boff = (row * 512 + ks * 64 + kgrp * 16) ^ ((row & 7) << 4);
                a[m] = *(const short8v*)((char*)XHs + boff);
            }
#pragma unroll
            for (int c = 0; c < 4; c++)
#pragma unroll
                for (int m = 0; m < 3; m++)
                    acc1[c][m] = __builtin_amdgcn_mfma_f32_16x16x32_bf16(
                        a[m], br[ks % 3][c], acc1[c][m], 0, 0, 0);
        }
    }
    __syncthreads();   // all GEMM1 A-reads done; H may overwrite X region

    // ---- agg1 (barrier-free): per chunk: YsT <- bf16(Y1), aggMFMA -> H ----
#pragma unroll
    for (int c = 0; c < 4; c++) {
#pragma unroll
        for (int m = 0; m < 3; m++) {
            int gr0 = m * 16 + kgrp * 4;
            ushort4 hq;
            hq.x = f2bf(acc1[c][m][0]); hq.y = f2bf(acc1[c][m][1]);
            hq.z = f2bf(acc1[c][m][2]); hq.w = f2bf(acc1[c][m][3]);
            int boff = (ncol * 128 + gr0 * 2) ^ ((ncol & 7) << 4);
            *(ushort4*)((char*)YsT + boff) = hq;
        }
        // same-wave LDS dependency only: compiler inserts lgkmcnt wait
        short8v yb[2];
#pragma unroll
        for (int ks = 0; ks < 2; ks++)
            yb[ks] = *(const short8v*)((char*)YsT +
                     ((ncol * 128 + ks * 64 + kgrp * 16) ^ ((ncol & 7) << 4)));
        float bv = b1[c * 64 + ncol];
#pragma unroll
        for (int mt = 0; mt < 3; mt++) {
            f32x4 o = (f32x4){0.f, 0.f, 0.f, 0.f};
#pragma unroll
            for (int ks = 0; ks < 2; ks++) {
                int ar = mt * 16 + l15;
                short8v af = *(const short8v*)((char*)AdjS +
                             ((ar * 128 + ks * 64 + kgrp * 16) ^ ((ar & 7) << 4)));
                o = __builtin_amdgcn_mfma_f32_16x16x32_bf16(af, yb[ks], o, 0, 0, 0);
            }
#pragma unroll
            for (int j = 0; j < 4; j++) {
                int grp = mt * 16 + kgrp * 4 + j;
                float s = sigm(o[j] + bv);
                int boff = (grp * 512 + (c * 64 + ncol) * 2) ^ ((grp & 7) << 4);
                *(ushort*)((char*)XHs + boff) = f2bf(s);   // H (aliased on X)
            }
        }
    }
    __syncthreads();   // H fully built before GEMM2 reads

    // ============ GEMM2 + agg2: two halves of 4 chunks (256 cols) ============
#pragma unroll 1
    for (int half = 0; half < 2; half++) {
        f32x4 acc[4][3];
#pragma unroll
        for (int c = 0; c < 4; c++)
#pragma unroll
            for (int m = 0; m < 3; m++) acc[c][m] = (f32x4){0.f, 0.f, 0.f, 0.f};

        const ushort* bpb = W2T + (size_t)(half * 256 + ncol) * 256 + kgrp * 8;
        short8v br[3][4];
#pragma unroll
        for (int c = 0; c < 4; c++)
            br[0][c] = *(const short8v*)(bpb + (size_t)c * 64 * 256);
#pragma unroll
        for (int c = 0; c < 4; c++)
            br[1][c] = *(const short8v*)(bpb + (size_t)c * 64 * 256 + 32);
#pragma unroll
        for (int ks = 0; ks < 8; ks++) {
            if (ks < 6) {
#pragma unroll
                for (int c = 0; c < 4; c++)
                    br[(ks + 2) % 3][c] =
                        *(const short8v*)(bpb + (size_t)c * 64 * 256 + (ks + 2) * 32);
            }
            short8v a[3];
#pragma unroll
            for (int m = 0; m < 3; m++) {
                int row = m * 16 + l15;
                int boff = (row * 512 + ks * 64 + kgrp * 16) ^ ((row & 7) << 4);
                a[m] = *(const short8v*)((char*)XHs + boff);
            }
#pragma unroll
            for (int c = 0; c < 4; c++)
#pragma unroll
                for (int m = 0; m < 3; m++)
                    acc[c][m] = __builtin_amdgcn_mfma_f32_16x16x32_bf16(
                        a[m], br[ks % 3][c], acc[c][m], 0, 0, 0);
        }

        // agg2 (barrier-free, per-wave YsT), direct out stores
#pragma unroll
        for (int c = 0; c < 4; c++) {
            int cg = half * 4 + c;
#pragma unroll
            for (int m = 0; m < 3; m++) {
                int gr0 = m * 16 + kgrp * 4;
                ushort4 hq;
                hq.x = f2bf(acc[c][m][0]); hq.y = f2bf(acc[c][m][1]);
                hq.z = f2bf(acc[c][m][2]); hq.w = f2bf(acc[c][m][3]);
                int boff = (ncol * 128 + gr0 * 2) ^ ((ncol & 7) << 4);
                *(ushort4*)((char*)YsT + boff) = hq;
            }
            short8v yb[2];
#pragma unroll
            for (int ks = 0; ks < 2; ks++)
                yb[ks] = *(const short8v*)((char*)YsT +
                         ((ncol * 128 + ks * 64 + kgrp * 16) ^ ((ncol & 7) << 4)));
            float bv = b2[cg * 64 + ncol];
#pragma unroll
            for (int mt = 0; mt < 3; mt++) {
                f32x4 o = (f32x4){0.f, 0.f, 0.f, 0.f};
#pragma unroll
                for (int ks = 0; ks < 2; ks++) {
                    int ar = mt * 16 + l15;
                    short8v af = *(const short8v*)((char*)AdjS +
                                 ((ar * 128 + ks * 64 + kgrp * 16) ^ ((ar & 7) << 4)));
                    o = __builtin_amdgcn_mfma_f32_16x16x32_bf16(af, yb[ks], o, 0, 0, 0);
                }
#pragma unroll
                for (int j = 0; j < 4; j++) {
                    int grp = mt * 16 + kgrp * 4 + j;
                    if (grp < MR) {
                        float s = sigm(o[j] + bv);
                        out[(size_t)(rowbase + grp) * 512 + cg * 64 + ncol] = s;
                    }
                }
            }
        }
    }
}

extern "C" void kernel_launch(void* const* d_in, const int* in_sizes, int n_in,
                              void* d_out, int out_size, void* d_ws, size_t ws_size,
                              hipStream_t stream) {
    const float* loc  = (const float*)d_in[0];
    const float* feat = (const float*)d_in[1];
    const int*   mask = (const int*)d_in[2];
    const float* past = (const float*)d_in[3];
    const float* W1   = (const float*)d_in[4];
    const float* b1   = (const float*)d_in[5];
    const float* W2   = (const float*)d_in[6];
    const float* b2   = (const float*)d_in[7];

    ushort* pairimg = (ushort*)d_ws;                        // 1024*3072 bf16 = 6 MB
    ushort* W1T     = pairimg + (size_t)(BATCH / 2) * 3072; // 256*512 bf16
    ushort* W2T     = W1T + 256 * 512;                      // 512*256 bf16

    adjpair_kernel<<<BATCH, 192, 0, stream>>>(loc, mask, past, pairimg);
    packT2_kernel<<<1024, 256, 0, stream>>>(W1, W2, W1T, W2T);

    fused_kernel<<<BATCH / GB, 256, 0, stream>>>(feat, pairimg, W1T, W2T, b1, b2,
                                                 (float*)d_out);
}